// Round 6
// baseline (183.609 us; speedup 1.0000x reference)
//
#include <hip/hip_runtime.h>
#include <math.h>

#define B_    64
#define N_    512
#define SEM_  256
#define STR_  256
#define DIM_  512              // SEM+STR
#define ROWS_ (B_*N_)          // 32768

// ---- workspace layout (float offsets) ----
#define OFF_T      0           // 256x256 f32 (Wbil@Wp temp)
#define OFF_QT16   65536       // 256x256 bf16, Qt[e][d] = Q[d][e]
#define OFF_W116   98304       // 256x256 bf16, W116[o][d] = Wfz[o][d]
#define OFF_W2T    131072      // 256x256 f32, W2t[d][o] = Wfz[o][256+d]
#define OFF_V1     196608      // 256  Wfz2 @ exparam
#define OFF_C1     196864      // 256  Wp^T (Wbil+Wbil^T) bp
#define OFF_H      197120      // 256
#define OFF_C0     197376      // 64 (1 used)
#define OFF_EV0    197440      // 64  Ev of row0 per batch
#define OFF_FV0    197504      // 64  fv of row0 per batch
#define OFF_FPART  197568      // 512 per-block fv partial sums
#define OFF_CNT    198080      // 64  uint batch arrival counters
#define OFF_V2BR   198144      // 64*256 raw Wfz2@sem0 (no E0 factor)
#define OFF_SUMP   214528      // 512*256 per-block sum_{j>=1} Ev_j*sem_j

typedef __bf16 bf16x8 __attribute__((ext_vector_type(8)));
typedef float  f32x4  __attribute__((ext_vector_type(4)));

__device__ __forceinline__ ushort f2b(float x) {
    return __builtin_bit_cast(ushort, (__bf16)x);   // native v_cvt (RTNE)
}
__device__ __forceinline__ float bflo(unsigned u) {
    return __builtin_bit_cast(float, u << 16);
}
__device__ __forceinline__ float bfhi(unsigned u) {
    return __builtin_bit_cast(float, u & 0xffff0000u);
}

// ============ K0a: T = Wbil@Wp ; W116 ; W2t ; v1, h, c0 ; zero cnt ============
__global__ __launch_bounds__(256) void k0a(
    const float* __restrict__ Wp, const float* __restrict__ bp,
    const float* __restrict__ Wbil, const float* __restrict__ Wfz,
    const float* __restrict__ exparam,
    float* __restrict__ T, ushort* __restrict__ W116, float* __restrict__ W2t,
    float* __restrict__ v1, float* __restrict__ h, float* __restrict__ c0,
    unsigned* __restrict__ cnt)
{
    int t = threadIdx.x, a = blockIdx.x;
    float acc = 0.f;
    const float* wb = Wbil + a*256;
#pragma unroll 16
    for (int c = 0; c < 256; ++c) acc += wb[c] * Wp[c*256 + t];
    T[a*256 + t] = acc;
    W116[a*256 + t] = f2b(Wfz[a*512 + t]);
    W2t[t*256 + a] = Wfz[a*512 + 256 + t];          // transposed Wfz2
    if (a == 0) {
        float s = 0.f;
        const float* w2 = Wfz + t*512 + 256;
#pragma unroll 16
        for (int dd = 0; dd < 256; ++dd) s += w2[dd] * exparam[dd];
        v1[t] = s;
    }
    if (a == 1) {
        float g = 0.f, g2 = 0.f;
#pragma unroll 8
        for (int c = 0; c < 256; ++c) {
            g  += Wbil[t*256 + c] * bp[c];
            g2 += Wbil[c*256 + t] * bp[c];
        }
        h[t] = g + g2;
        __shared__ float red[256];
        red[t] = bp[t] * g;
        __syncthreads();
        for (int s2 = 128; s2 > 0; s2 >>= 1) {
            if (t < s2) red[t] += red[t + s2];
            __syncthreads();
        }
        if (t == 0) c0[0] = red[0];
    }
    if (a == 2 && t < 64) cnt[t] = 0u;
}

// ============ K0b: Qt16[e][t] = bf16(Q[t][e]) coalesced ; c1 ============
__global__ __launch_bounds__(256) void k0b(
    const float* __restrict__ Wp, const float* __restrict__ T,
    const float* __restrict__ h,
    ushort* __restrict__ Qt16, float* __restrict__ c1)
{
    int t = threadIdx.x, e = blockIdx.x;
    float acc = 0.f;
#pragma unroll 16
    for (int a2 = 0; a2 < 256; ++a2) acc += Wp[a2*256 + t] * T[a2*256 + e];
    Qt16[e*256 + t] = f2b(acc);          // Qt[e][d=t] = Q[d][e], coalesced store
    __shared__ float red[256];
    red[t] = Wp[t*256 + e] * h[t];
    __syncthreads();
    for (int s2 = 128; s2 > 0; s2 >>= 1) {
        if (t < s2) red[t] += red[t + s2];
        __syncthreads();
    }
    if (t == 0) c1[e] = red[0];
}

// ============ K_FUSED: rowstats + batch-barrier + final, per-batch sync ============
// LDS 53248B -> 3 blocks/CU guaranteed; 512 blocks all co-resident (>=2/CU worst case).
__global__ __launch_bounds__(256, 3) void k_fused(
    const float* __restrict__ input, const ushort* __restrict__ Qt16,
    const ushort* __restrict__ W116, const float* __restrict__ W2t,
    const float* __restrict__ c1, const float* __restrict__ c0,
    const float* __restrict__ Wfi, const float* __restrict__ bbil,
    const float* __restrict__ bfi, const float* __restrict__ v1,
    const float* __restrict__ bfz,
    float* __restrict__ Ev0g, float* __restrict__ Fv0g,
    float* __restrict__ Fpart, unsigned* __restrict__ cnt,
    float* __restrict__ v2braw, float* __restrict__ sumpart,
    float* __restrict__ out)
{
    __shared__ __align__(16) char smem[53248];
    ushort* Ash  = (ushort*)smem;              // 32768: A tile (str, then sem); Csh overlay
    ushort* Ush  = (ushort*)(smem + 32768);    // 16384: U' halves; sumred overlay
    float*  rgA  = (float*)(smem + 49152);     // 1024: sdiag[64][4] / s0sh[256] / sumvec[256]
    float*  rgB  = (float*)(smem + 50176);     // 1024: fdiag[64][4] / vred[32][8]
    float*  EvL  = (float*)(smem + 51200);     // 64
    float*  FvL  = (float*)(smem + 51456);     // 64
    float*  cAs  = (float*)(smem + 51712);     // 64
    float*  cBs  = (float*)(smem + 51968);     // 64
    float*  a0sh = (float*)(smem + 52224);     // 256

    int t = threadIdx.x;
    int lane = t & 63, w = t >> 6;
    int g = lane >> 4, li = lane & 15;
    int bk = blockIdx.x;
    int b = bk >> 3, rt = bk & 7;
    long rowbase = (long)b*512 + rt*64;
    int i0 = rt*64;
    const float* AbS = input + rowbase*DIM_ + SEM_;  // str half
    const float* AbM = input + rowbase*DIM_;         // sem half
    int xs = (li & 7) << 3;

    // ======== PHASE 1: stage str tile (bf16, swizzled) ========
#pragma unroll
    for (int q = 0; q < 16; ++q) {
        int v = t + 256*q;
        int r = v >> 6, c4 = v & 63;
        float4 a4 = *(const float4*)(AbS + (long)r*DIM_ + c4*4);
        ushort4 b4 = make_ushort4(f2b(a4.x), f2b(a4.y), f2b(a4.z), f2b(a4.w));
        *(ushort4*)&Ash[r*256 + ((c4*4) ^ ((r & 7) << 3))] = b4;
    }
    __syncthreads();

    f32x4 acc[4][4];
#pragma unroll
    for (int m = 0; m < 4; ++m)
#pragma unroll
        for (int n = 0; n < 4; ++n) acc[m][n] = (f32x4){0.f, 0.f, 0.f, 0.f};

#pragma unroll 4
    for (int k0 = 0; k0 < 256; k0 += 32) {
        bf16x8 af[4], bfr[4];
#pragma unroll
        for (int n = 0; n < 4; ++n)
            bfr[n] = *(const bf16x8*)&Qt16[(w*64 + n*16 + li)*256 + k0 + g*8];
#pragma unroll
        for (int m = 0; m < 4; ++m)
            af[m] = *(const bf16x8*)&Ash[(m*16 + li)*256 + ((k0 + g*8) ^ xs)];
#pragma unroll
        for (int m = 0; m < 4; ++m)
#pragma unroll
            for (int n = 0; n < 4; ++n)
                acc[m][n] = __builtin_amdgcn_mfma_f32_16x16x32_bf16(af[m], bfr[n], acc[m][n], 0, 0, 0);
    }

    // ---- diag epilogue: s = diag(U' Str^T), f = Wfi variant; U' in halved LDS ----
    {
        float c1v[4];
#pragma unroll
        for (int n = 0; n < 4; ++n) c1v[n] = c1[w*64 + n*16 + li];

        f32x4 dacc[4], facc[4];
#pragma unroll
        for (int m = 0; m < 4; ++m) { dacc[m] = (f32x4){0.f,0.f,0.f,0.f}; facc[m] = (f32x4){0.f,0.f,0.f,0.f}; }

#pragma unroll
        for (int hv = 0; hv < 2; ++hv) {
            if ((w >> 1) == hv) {
                int cl0 = (w & 1)*64;
#pragma unroll
                for (int m = 0; m < 4; ++m)
#pragma unroll
                    for (int n = 0; n < 4; ++n)
#pragma unroll
                        for (int reg = 0; reg < 4; ++reg) {
                            int row = m*16 + g*4 + reg;
                            int cl = cl0 + n*16 + li;
                            Ush[row*128 + (cl ^ ((row & 7) << 3))] = f2b(acc[m][n][reg] + c1v[n]);
                        }
            }
            __syncthreads();
            int kb = w*32 + g*8;
            int kg = hv*128 + kb;
            float4 wf0 = *(const float4*)(Wfi + kg);
            float4 wf1 = *(const float4*)(Wfi + kg + 4);
            bf16x8 afw = (bf16x8){(__bf16)wf0.x, (__bf16)wf0.y, (__bf16)wf0.z, (__bf16)wf0.w,
                                  (__bf16)wf1.x, (__bf16)wf1.y, (__bf16)wf1.z, (__bf16)wf1.w};
#pragma unroll
            for (int m = 0; m < 4; ++m) {
                bf16x8 afu = *(const bf16x8*)&Ush[(m*16 + li)*128 + (kb ^ xs)];
                bf16x8 bfs = *(const bf16x8*)&Ash[(m*16 + li)*256 + (kg ^ xs)];
                dacc[m] = __builtin_amdgcn_mfma_f32_16x16x32_bf16(afu, bfs, dacc[m], 0, 0, 0);
                facc[m] = __builtin_amdgcn_mfma_f32_16x16x32_bf16(afw, bfs, facc[m], 0, 0, 0);
            }
            __syncthreads();
        }

        // diag extraction -> rgA (sdiag), rgB (fdiag)
        if (g == (li >> 2)) {
            int dr = li & 3;
#pragma unroll
            for (int m = 0; m < 4; ++m) {
                float dv = dr == 0 ? dacc[m][0] : dr == 1 ? dacc[m][1] : dr == 2 ? dacc[m][2] : dacc[m][3];
                rgA[(m*16 + li)*4 + w] = dv;
            }
        }
        if (g == 0) {
#pragma unroll
            for (int m = 0; m < 4; ++m) rgB[(m*16 + li)*4 + w] = facc[m][0];
        }
    }
    __syncthreads();

    // ======== E1: per-row stats + stage sem tile + s0sh ========
    if (t < 64) {
        float ss = rgA[t*4] + rgA[t*4+1] + rgA[t*4+2] + rgA[t*4+3];
        float ff = rgB[t*4] + rgB[t*4+1] + rgB[t*4+2] + rgB[t*4+3];
        float ev = expf(ss + c0[0] + bbil[0]);
        float fr = expf(ff + bfi[0]);
        FvL[t] = fr;
        EvL[t] = (rt == 0 && t == 0) ? 0.f : ev;    // exclude j=0 from sump
        if (rt == 0 && t == 0) { Ev0g[b] = ev; Fv0g[b] = fr; }
        float fs = fr;
#pragma unroll
        for (int off = 32; off >= 1; off >>= 1) fs += __shfl_down(fs, off);
        if (t == 0) Fpart[bk] = fs;
        // stage sem row 0 of this batch into rgA (s0sh); after rgA reads above
        *(float4*)&rgA[t*4] = *(const float4*)(input + (long)b*512*DIM_ + t*4);
    }
    // stage sem tile into Ash (overwrites str; all str reads done)
#pragma unroll
    for (int q = 0; q < 16; ++q) {
        int v = t + 256*q;
        int r = v >> 6, c4 = v & 63;
        float4 a4 = *(const float4*)(AbM + (long)r*DIM_ + c4*4);
        ushort4 b4 = make_ushort4(f2b(a4.x), f2b(a4.y), f2b(a4.z), f2b(a4.w));
        *(ushort4*)&Ash[r*256 + ((c4*4) ^ ((r & 7) << 3))] = b4;
    }
    __syncthreads();

    // ======== E2: sump partials (Ush overlay) + v2b slice partials (rgB) ========
    {
        float* sumred = (float*)Ush;
        int qq = t >> 5, c8 = t & 31;
        float p[8];
#pragma unroll
        for (int i = 0; i < 8; ++i) p[i] = 0.f;
#pragma unroll
        for (int rr = 0; rr < 8; ++rr) {
            int r = qq*8 + rr;
            float ev = EvL[r];
            uint4 uv = *(const uint4*)&Ash[r*256 + ((c8*8) ^ (rr << 3))];
            p[0] += ev * bflo(uv.x); p[1] += ev * bfhi(uv.x);
            p[2] += ev * bflo(uv.y); p[3] += ev * bfhi(uv.y);
            p[4] += ev * bflo(uv.z); p[5] += ev * bfhi(uv.z);
            p[6] += ev * bflo(uv.w); p[7] += ev * bfhi(uv.w);
        }
        *(float4*)&sumred[qq*256 + c8*8]     = (float4){p[0], p[1], p[2], p[3]};
        *(float4*)&sumred[qq*256 + c8*8 + 4] = (float4){p[4], p[5], p[6], p[7]};

        // v2b raw slice: cols [rt*32, rt*32+32), 8-way split over depth
        int colL = t & 31, part = t >> 5;
        float vp = 0.f;
#pragma unroll 8
        for (int dd = 0; dd < 32; ++dd) {
            int d = part*32 + dd;
            vp += W2t[d*256 + rt*32 + colL] * rgA[d];
        }
        rgB[colL*8 + part] = vp;
    }
    __syncthreads();

    // ======== E3: reduce + global writes + arrive ========
    {
        float* sumred = (float*)Ush;
        float sp = 0.f;
#pragma unroll
        for (int qq = 0; qq < 8; ++qq) sp += sumred[qq*256 + t];
        sumpart[(long)bk*256 + t] = sp;
        if (t < 32) {
            float v = 0.f;
#pragma unroll
            for (int p = 0; p < 8; ++p) v += rgB[t*8 + p];
            v2braw[b*256 + rt*32 + t] = v;
        }
    }
    __threadfence();
    __syncthreads();
    if (t == 0)
        __hip_atomic_fetch_add(&cnt[b], 1u, __ATOMIC_RELEASE, __HIP_MEMORY_SCOPE_AGENT);

    // ======== per-batch barrier: wait for all 8 blocks ========
    while (__hip_atomic_load(&cnt[b], __ATOMIC_ACQUIRE, __HIP_MEMORY_SCOPE_AGENT) < 8u)
        __builtin_amdgcn_s_sleep(2);

    // ======== PHASE 2 setup ========
    float Ftot = 0.f;
#pragma unroll
    for (int p = 0; p < 8; ++p) Ftot += Fpart[b*8 + p];
    float invF = 1.0f / Ftot;
    float E0 = Ev0g[b], f0v = Fv0g[b];
    if (t < 64) {
        float fr = FvL[t], ev = EvL[t];
        cAs[t] = fr * invF;
        cBs[t] = ((i0 + t) == 0) ? -invF
               : (1.0f + (f0v - fr)*invF) / (512.0f * ev);
    }
    if (rt == 0) {   // gather sumvec into rgA
        float sv = 0.f;
#pragma unroll
        for (int p = 0; p < 8; ++p) sv += sumpart[(long)(b*8 + p)*256 + t];
        rgA[t] = sv;
    }
    __syncthreads();

    // k-loop 2: sem (already in Ash) @ Wfz1^T
#pragma unroll
    for (int m = 0; m < 4; ++m)
#pragma unroll
        for (int n = 0; n < 4; ++n) acc[m][n] = (f32x4){0.f, 0.f, 0.f, 0.f};

#pragma unroll 4
    for (int k0 = 0; k0 < 256; k0 += 32) {
        bf16x8 af[4], bfr[4];
#pragma unroll
        for (int n = 0; n < 4; ++n)
            bfr[n] = *(const bf16x8*)&W116[(w*64 + n*16 + li)*256 + k0 + g*8];
#pragma unroll
        for (int m = 0; m < 4; ++m)
            af[m] = *(const bf16x8*)&Ash[(m*16 + li)*256 + ((k0 + g*8) ^ xs)];
#pragma unroll
        for (int m = 0; m < 4; ++m)
#pragma unroll
            for (int n = 0; n < 4; ++n)
                acc[m][n] = __builtin_amdgcn_mfma_f32_16x16x32_bf16(af[m], bfr[n], acc[m][n], 0, 0, 0);
    }

    // rt0: a0[col] = W2t^T-dot with sumvec (row-0 correction)
    if (rt == 0) {
        float a0 = 0.f;
#pragma unroll 16
        for (int d = 0; d < 256; ++d) a0 += W2t[d*256 + t] * rgA[d];
        a0sh[t] = a0;
    }

    // epilogue vectors
    float v1v[4], v2v[4], bzv[4];
#pragma unroll
    for (int n = 0; n < 4; ++n) {
        int col = w*64 + n*16 + li;
        v1v[n] = v1[col];
        v2v[n] = E0 * v2braw[b*256 + col];
        bzv[n] = bfz[col];
    }

    // two-half Csh repack (overlays Ash; stride 256, XOR col^(g<<3))
    float* Csh = (float*)Ash;
#pragma unroll
    for (int hh = 0; hh < 2; ++hh) {
        __syncthreads();
#pragma unroll
        for (int mm = 0; mm < 2; ++mm) {
            int m = hh*2 + mm;
#pragma unroll
            for (int reg = 0; reg < 4; ++reg) {
                int row = m*16 + g*4 + reg;
                int row_l = row - hh*32;
                int sw = ((row_l >> 2) & 3) << 3;
                float ca = cAs[row], cb = cBs[row];
                int irow = i0 + row;
#pragma unroll
                for (int n = 0; n < 4; ++n) {
                    int col = w*64 + n*16 + li;
                    float sel = (irow == 0) ? a0sh[col] : v2v[n];
                    float val = acc[m][n][reg] + ca*v1v[n] + cb*sel + bzv[n];
                    Csh[row_l*256 + (col ^ sw)] = fmaxf(val, 0.f);
                }
            }
        }
        __syncthreads();
#pragma unroll
        for (int q = 0; q < 8; ++q) {
            int v = t + 256*q;
            int r = v >> 6, c4 = v & 63;
            int sw = ((r >> 2) & 3) << 3;
            *(float4*)(out + (rowbase + hh*32 + r)*256 + c4*4) =
                *(const float4*)&Csh[r*256 + ((c4*4) ^ sw)];
        }
    }
}

extern "C" void kernel_launch(void* const* d_in, const int* in_sizes, int n_in,
                              void* d_out, int out_size, void* d_ws, size_t ws_size,
                              hipStream_t stream) {
    const float* input   = (const float*)d_in[0];
    const float* Wp      = (const float*)d_in[1];
    const float* bp      = (const float*)d_in[2];
    const float* Wbil    = (const float*)d_in[3];
    const float* bbil    = (const float*)d_in[4];
    const float* Wfi     = (const float*)d_in[5];
    const float* bfi     = (const float*)d_in[6];
    const float* exparam = (const float*)d_in[7];
    const float* Wfz     = (const float*)d_in[8];
    const float* bfz     = (const float*)d_in[9];
    float* ws  = (float*)d_ws;
    float* out = (float*)d_out;

    float*    T      = ws + OFF_T;
    ushort*   Qt16   = (ushort*)(ws + OFF_QT16);
    ushort*   W116   = (ushort*)(ws + OFF_W116);
    float*    W2t    = ws + OFF_W2T;
    float*    v1     = ws + OFF_V1;
    float*    c1     = ws + OFF_C1;
    float*    h      = ws + OFF_H;
    float*    c0     = ws + OFF_C0;
    float*    Ev0g   = ws + OFF_EV0;
    float*    Fv0g   = ws + OFF_FV0;
    float*    Fpart  = ws + OFF_FPART;
    unsigned* cnt    = (unsigned*)(ws + OFF_CNT);
    float*    v2braw = ws + OFF_V2BR;
    float*    sumpart= ws + OFF_SUMP;

    k0a<<<256, 256, 0, stream>>>(Wp, bp, Wbil, Wfz, exparam, T, W116, W2t, v1, h, c0, cnt);
    k0b<<<256, 256, 0, stream>>>(Wp, T, h, Qt16, c1);
    k_fused<<<ROWS_/64, 256, 0, stream>>>(input, Qt16, W116, W2t, c1, c0, Wfi, bbil, bfi,
                                          v1, bfz, Ev0g, Fv0g, Fpart, cnt, v2braw, sumpart, out);
}

// Round 7
// 106.775 us; speedup vs baseline: 1.7196x; 1.7196x over previous
//
#include <hip/hip_runtime.h>
#include <math.h>

#define B_    64
#define N_    512
#define SEM_  256
#define STR_  256
#define DIM_  512              // SEM+STR
#define ROWS_ (B_*N_)          // 32768

// ---- workspace layout (float offsets) ----
#define OFF_T      0           // 256x256 f32 (Wbil@Wp temp)
#define OFF_QT16   65536       // 256x256 bf16, Qt[e][d] = Q[d][e]
#define OFF_W116   98304       // 256x256 bf16, W116[o][d] = Wfz[o][d]
#define OFF_W2T    131072      // 256x256 f32, W2t[d][o] = Wfz[o][256+d]
#define OFF_V1     196608      // 256  Wfz2 @ exparam
#define OFF_C1     196864      // 256  Wp^T (Wbil+Wbil^T) bp
#define OFF_H      197120      // 256
#define OFF_C0     197376      // 1 (padded)
#define OFF_EV     197440      // 32768
#define OFF_FV     230208      // 32768
#define OFF_SUMP   262976      // 512*256 per-block partial sums
#define OFF_V2B    394048      // 64*256
#define OFF_ROW0   410432      // 64*256 pre-ReLU row-0 GEMM results

typedef __bf16 bf16x8 __attribute__((ext_vector_type(8)));
typedef float  f32x4  __attribute__((ext_vector_type(4)));

__device__ __forceinline__ ushort f2b(float x) {
    return __builtin_bit_cast(ushort, (__bf16)x);   // native v_cvt (RTNE)
}
__device__ __forceinline__ float bflo(unsigned u) {
    return __builtin_bit_cast(float, u << 16);
}
__device__ __forceinline__ float bfhi(unsigned u) {
    return __builtin_bit_cast(float, u & 0xffff0000u);
}

// ============ K0a: T = Wbil@Wp ; W116 ; W2t ; v1, h, c0 ============
__global__ __launch_bounds__(256) void k0a(
    const float* __restrict__ Wp, const float* __restrict__ bp,
    const float* __restrict__ Wbil, const float* __restrict__ Wfz,
    const float* __restrict__ exparam,
    float* __restrict__ T, ushort* __restrict__ W116, float* __restrict__ W2t,
    float* __restrict__ v1, float* __restrict__ h, float* __restrict__ c0)
{
    int t = threadIdx.x, a = blockIdx.x;
    float acc = 0.f;
    const float* wb = Wbil + a*256;
#pragma unroll 16
    for (int c = 0; c < 256; ++c) acc += wb[c] * Wp[c*256 + t];
    T[a*256 + t] = acc;
    W116[a*256 + t] = f2b(Wfz[a*512 + t]);
    W2t[t*256 + a] = Wfz[a*512 + 256 + t];          // transposed Wfz2
    if (a == 0) {
        float s = 0.f;
        const float* w2 = Wfz + t*512 + 256;
#pragma unroll 16
        for (int dd = 0; dd < 256; ++dd) s += w2[dd] * exparam[dd];
        v1[t] = s;
    }
    if (a == 1) {
        float g = 0.f, g2 = 0.f;
#pragma unroll 8
        for (int c = 0; c < 256; ++c) {
            g  += Wbil[t*256 + c] * bp[c];
            g2 += Wbil[c*256 + t] * bp[c];
        }
        h[t] = g + g2;
        __shared__ float red[256];
        red[t] = bp[t] * g;
        __syncthreads();
        for (int s2 = 128; s2 > 0; s2 >>= 1) {
            if (t < s2) red[t] += red[t + s2];
            __syncthreads();
        }
        if (t == 0) c0[0] = red[0];
    }
}

// ============ K0b: Qt16[e][t] = bf16(Q[t][e]) coalesced ; c1 ============
__global__ __launch_bounds__(256) void k0b(
    const float* __restrict__ Wp, const float* __restrict__ T,
    const float* __restrict__ h,
    ushort* __restrict__ Qt16, float* __restrict__ c1)
{
    int t = threadIdx.x, e = blockIdx.x;
    float acc = 0.f;
#pragma unroll 16
    for (int a2 = 0; a2 < 256; ++a2) acc += Wp[a2*256 + t] * T[a2*256 + e];
    Qt16[e*256 + t] = f2b(acc);          // Qt[e][d=t] = Q[d][e], coalesced store
    __shared__ float red[256];
    red[t] = Wp[t*256 + e] * h[t];
    __syncthreads();
    for (int s2 = 128; s2 > 0; s2 >>= 1) {
        if (t < s2) red[t] += red[t + s2];
        __syncthreads();
    }
    if (t == 0) c1[e] = red[0];
}

// ============ K1: MFMA GEMM u = str@Q -> Ev, fv via diag-MFMA ============
// B (Qt16) read direct from L2 -> barrier-free k-loop. LDS ~68KB -> 2 blocks/CU.
__global__ __launch_bounds__(256) void k_rowstats(
    const float* __restrict__ input, const ushort* __restrict__ Qt16,
    const float* __restrict__ c1, const float* __restrict__ c0,
    const float* __restrict__ Wfi, const float* __restrict__ bbil,
    const float* __restrict__ bfi, const float* __restrict__ W2t,
    float* __restrict__ Ev, float* __restrict__ fv, float* __restrict__ v2b)
{
    __shared__ __align__(16) char smem[69632];
    ushort* Ash   = (ushort*)smem;              // [64][256] bf16, XOR-swizzled
    ushort* Ush   = (ushort*)(smem + 32768);    // [64][256] bf16 swz (U')
    float*  sdiag = (float*)(smem + 65536);     // [64][4]
    float*  fdiag = (float*)(smem + 66560);     // [64][4]
    float*  s0sh  = (float*)(smem + 67584);     // [256]
    float*  shE0  = (float*)(smem + 68608);

    int t = threadIdx.x;
    int lane = t & 63, w = t >> 6;
    int g = lane >> 4, li = lane & 15;
    long rowbase = (long)blockIdx.x * 64;
    int b = (int)(rowbase >> 9);
    int i0 = (int)(rowbase & 511);
    const float* Ab = input + rowbase*DIM_ + SEM_;   // str half
    int xs = (li & 7) << 3;

    // stage A (str) tile: fp32 -> bf16, swizzled
#pragma unroll
    for (int q = 0; q < 16; ++q) {
        int v = t + 256*q;
        int r = v >> 6, c4 = v & 63;
        float4 a4 = *(const float4*)(Ab + (long)r*DIM_ + c4*4);
        ushort4 b4 = make_ushort4(f2b(a4.x), f2b(a4.y), f2b(a4.z), f2b(a4.w));
        *(ushort4*)&Ash[r*256 + ((c4*4) ^ ((r & 7) << 3))] = b4;
    }
    __syncthreads();

    f32x4 acc[4][4];
#pragma unroll
    for (int m = 0; m < 4; ++m)
#pragma unroll
        for (int n = 0; n < 4; ++n) acc[m][n] = (f32x4){0.f, 0.f, 0.f, 0.f};

#pragma unroll 4
    for (int k0 = 0; k0 < 256; k0 += 32) {
        bf16x8 af[4], bfr[4];
#pragma unroll
        for (int n = 0; n < 4; ++n)
            bfr[n] = *(const bf16x8*)&Qt16[(w*64 + n*16 + li)*256 + k0 + g*8];
#pragma unroll
        for (int m = 0; m < 4; ++m)
            af[m] = *(const bf16x8*)&Ash[(m*16 + li)*256 + ((k0 + g*8) ^ xs)];
#pragma unroll
        for (int m = 0; m < 4; ++m)
#pragma unroll
            for (int n = 0; n < 4; ++n)
                acc[m][n] = __builtin_amdgcn_mfma_f32_16x16x32_bf16(af[m], bfr[n], acc[m][n], 0, 0, 0);
    }

    // ---- U' = u + c1 -> Ush (bf16, swizzled) ----
    float c1v[4];
#pragma unroll
    for (int n = 0; n < 4; ++n) c1v[n] = c1[w*64 + n*16 + li];
#pragma unroll
    for (int m = 0; m < 4; ++m)
#pragma unroll
        for (int n = 0; n < 4; ++n)
#pragma unroll
            for (int reg = 0; reg < 4; ++reg) {
                int row = m*16 + g*4 + reg;
                int col = w*64 + n*16 + li;
                Ush[row*256 + (col ^ ((row & 7) << 3))] = f2b(acc[m][n][reg] + c1v[n]);
            }
    __syncthreads();

    // ---- diag MFMA: s = diag(U' @ Str^T), f = Wfi-broadcast variant ----
    f32x4 dacc[4], facc[4];
#pragma unroll
    for (int m = 0; m < 4; ++m) { dacc[m] = (f32x4){0.f,0.f,0.f,0.f}; facc[m] = (f32x4){0.f,0.f,0.f,0.f}; }
#pragma unroll
    for (int kk = 0; kk < 2; ++kk) {
        int kb = (w*2 + kk)*32 + g*8;
        float4 wf0 = *(const float4*)(Wfi + kb);
        float4 wf1 = *(const float4*)(Wfi + kb + 4);
        bf16x8 afw = (bf16x8){(__bf16)wf0.x, (__bf16)wf0.y, (__bf16)wf0.z, (__bf16)wf0.w,
                              (__bf16)wf1.x, (__bf16)wf1.y, (__bf16)wf1.z, (__bf16)wf1.w};
#pragma unroll
        for (int m = 0; m < 4; ++m) {
            int ridx = (m*16 + li)*256 + (kb ^ xs);
            bf16x8 afu = *(const bf16x8*)&Ush[ridx];
            bf16x8 bfs = *(const bf16x8*)&Ash[ridx];
            dacc[m] = __builtin_amdgcn_mfma_f32_16x16x32_bf16(afu, bfs, dacc[m], 0, 0, 0);
            facc[m] = __builtin_amdgcn_mfma_f32_16x16x32_bf16(afw, bfs, facc[m], 0, 0, 0);
        }
    }
    // extract diagonal: lane owns D[row=g*4+reg][col=li]; diag when li == g*4+reg
    if (g == (li >> 2)) {
        int dr = li & 3;
#pragma unroll
        for (int m = 0; m < 4; ++m) {
            float dv = dr == 0 ? dacc[m][0] : dr == 1 ? dacc[m][1] : dr == 2 ? dacc[m][2] : dacc[m][3];
            sdiag[(m*16 + li)*4 + w] = dv;
        }
    }
    if (g == 0) {
#pragma unroll
        for (int m = 0; m < 4; ++m) fdiag[(m*16 + li)*4 + w] = facc[m][0];
    }
    __syncthreads();
    if (t < 64) {
        float ss = sdiag[t*4] + sdiag[t*4+1] + sdiag[t*4+2] + sdiag[t*4+3];
        float ff = fdiag[t*4] + fdiag[t*4+1] + fdiag[t*4+2] + fdiag[t*4+3];
        float ev = expf(ss + c0[0] + bbil[0]);
        Ev[rowbase + t] = ev;
        fv[rowbase + t] = expf(ff + bfi[0]);
        if (t == 0) shE0[0] = ev;
    }

    // v2b for the block owning batch row 0
    if (i0 == 0) {
        if (t < 64)
            *(float4*)&s0sh[t*4] = *(const float4*)(input + (long)b*512*DIM_ + t*4);
        __syncthreads();
        float a2 = 0.f;
#pragma unroll 8
        for (int d = 0; d < 256; ++d) a2 += W2t[d*256 + t] * s0sh[d];
        v2b[b*256 + t] = shE0[0] * a2;
    }
}

// ============ K3: MFMA GEMM sem@Wfz1^T + epilogue + sump partials ============
// B (W116) read direct from L2 -> barrier-free k-loop.
__global__ __launch_bounds__(256) void k_final(
    const float* __restrict__ input, const ushort* __restrict__ W116,
    const float* __restrict__ v1, const float* __restrict__ v2b,
    const float* __restrict__ Ev, const float* __restrict__ fv,
    const float* __restrict__ bfz,
    float* __restrict__ sump, float* __restrict__ row0pre,
    float* __restrict__ out)
{
    __shared__ __align__(16) char smem[62976];
    ushort* Ash    = (ushort*)smem;             // [64][256] bf16 swz
    float*  Csh    = (float*)smem;              // [32][264] f32 (epilogue overlay)
    float*  sumred = (float*)(smem + 53248);    // [8][256]
    float*  cAs    = (float*)(smem + 61440);    // 64
    float*  cBs    = (float*)(smem + 61696);    // 64
    float*  EvL    = (float*)(smem + 61952);    // 64
    float*  wred   = (float*)(smem + 62208);    // 4

    int t = threadIdx.x;
    int lane = t & 63, w = t >> 6;
    int g = lane >> 4, li = lane & 15;
    long rowbase = (long)blockIdx.x * 64;
    int b = (int)(rowbase >> 9);
    int i0 = (int)(rowbase & 511);
    const float* Ab = input + rowbase*DIM_;          // sem half
    int xs = (li & 7) << 3;

    // Fws = sum fv over batch via wave-shuffle reduce
    float fsum = fv[b*512 + t] + fv[b*512 + 256 + t];
#pragma unroll
    for (int off = 32; off >= 1; off >>= 1) fsum += __shfl_down(fsum, off);
    if (lane == 0) wred[w] = fsum;
    __syncthreads();
    float invF = 1.0f / (wred[0] + wred[1] + wred[2] + wred[3]);

    if (t < 64) {
        int row = (int)rowbase + t;
        float fr = fv[row];
        float ev = Ev[row];
        EvL[t] = (i0 == 0 && t == 0) ? 0.f : ev;     // exclude j=0 from sump
        cAs[t] = fr * invF;                          // d0
        cBs[t] = ((i0 + t) == 0) ? -invF
               : (1.0f + (fv[b*512] - fr)*invF) / (512.0f * ev);
    }

    // stage A (sem) tile, swizzled
#pragma unroll
    for (int q = 0; q < 16; ++q) {
        int v = t + 256*q;
        int r = v >> 6, c4 = v & 63;
        float4 a4 = *(const float4*)(Ab + (long)r*DIM_ + c4*4);
        ushort4 b4 = make_ushort4(f2b(a4.x), f2b(a4.y), f2b(a4.z), f2b(a4.w));
        *(ushort4*)&Ash[r*256 + ((c4*4) ^ ((r & 7) << 3))] = b4;
    }
    __syncthreads();

    f32x4 acc[4][4];
#pragma unroll
    for (int m = 0; m < 4; ++m)
#pragma unroll
        for (int n = 0; n < 4; ++n) acc[m][n] = (f32x4){0.f, 0.f, 0.f, 0.f};

#pragma unroll 4
    for (int k0 = 0; k0 < 256; k0 += 32) {
        bf16x8 af[4], bfr[4];
#pragma unroll
        for (int n = 0; n < 4; ++n)
            bfr[n] = *(const bf16x8*)&W116[(w*64 + n*16 + li)*256 + k0 + g*8];
#pragma unroll
        for (int m = 0; m < 4; ++m)
            af[m] = *(const bf16x8*)&Ash[(m*16 + li)*256 + ((k0 + g*8) ^ xs)];
#pragma unroll
        for (int m = 0; m < 4; ++m)
#pragma unroll
            for (int n = 0; n < 4; ++n)
                acc[m][n] = __builtin_amdgcn_mfma_f32_16x16x32_bf16(af[m], bfr[n], acc[m][n], 0, 0, 0);
    }

    // ---- sump partial: sum_{j in block, j!=0} Ev_j * sem[j][d], vectorized ----
    {
        int qq = t >> 5, c8 = t & 31;
        float p[8];
#pragma unroll
        for (int i = 0; i < 8; ++i) p[i] = 0.f;
#pragma unroll
        for (int rr = 0; rr < 8; ++rr) {
            int r = qq*8 + rr;
            float ev = EvL[r];
            uint4 uv = *(const uint4*)&Ash[r*256 + ((c8*8) ^ (rr << 3))];
            p[0] += ev * bflo(uv.x); p[1] += ev * bfhi(uv.x);
            p[2] += ev * bflo(uv.y); p[3] += ev * bfhi(uv.y);
            p[4] += ev * bflo(uv.z); p[5] += ev * bfhi(uv.z);
            p[6] += ev * bflo(uv.w); p[7] += ev * bfhi(uv.w);
        }
        *(float4*)&sumred[qq*256 + c8*8]     = (float4){p[0], p[1], p[2], p[3]};
        *(float4*)&sumred[qq*256 + c8*8 + 4] = (float4){p[4], p[5], p[6], p[7]};
    }
    __syncthreads();
    {
        float sp = 0.f;
#pragma unroll
        for (int qq = 0; qq < 8; ++qq) sp += sumred[qq*256 + t];
        sump[(long)blockIdx.x*256 + t] = sp;
    }

    // epilogue vectors
    float v1v[4], v2v[4], bzv[4];
#pragma unroll
    for (int n = 0; n < 4; ++n) {
        int col = w*64 + n*16 + li;
        v1v[n] = v1[col];
        v2v[n] = v2b[b*256 + col];
        bzv[n] = bfz[col];
    }

    // two-half LDS repack (Csh overlaps Ash; all Ash reads completed above)
#pragma unroll
    for (int hh = 0; hh < 2; ++hh) {
        __syncthreads();
#pragma unroll
        for (int mm = 0; mm < 2; ++mm) {
            int m = hh*2 + mm;
#pragma unroll
            for (int reg = 0; reg < 4; ++reg) {
                int row = m*16 + g*4 + reg;
                float ca = cAs[row], cb = cBs[row];
                int irow = i0 + row;
#pragma unroll
                for (int n = 0; n < 4; ++n) {
                    int col = w*64 + n*16 + li;
                    float sel = (irow == 0) ? 0.f : v2v[n];
                    float val = acc[m][n][reg] + ca*v1v[n] + cb*sel + bzv[n];
                    if (irow == 0) row0pre[b*256 + col] = val;   // pre-ReLU, no v0 term
                    Csh[(row - hh*32)*264 + col] = fmaxf(val, 0.f);
                }
            }
        }
        __syncthreads();
#pragma unroll
        for (int q = 0; q < 8; ++q) {
            int v = t + 256*q;
            int r = v >> 6, c4 = v & 63;
            *(float4*)(out + (rowbase + hh*32 + r)*256 + c4*4) = *(const float4*)&Csh[r*264 + c4*4];
        }
    }
}

// ============ K4: fixup row i=0 of each batch ============
__global__ __launch_bounds__(256) void k_fix(
    const float* __restrict__ sump, const float* __restrict__ fv,
    const float* __restrict__ W2t, const float* __restrict__ row0pre,
    float* __restrict__ out)
{
    int b = blockIdx.x, t = threadIdx.x;
    __shared__ float svsh[256];
    __shared__ float redF[256];
    float a = 0.f;
#pragma unroll
    for (int p = 0; p < 8; ++p) a += sump[(long)(b*8 + p)*256 + t];
    svsh[t] = a;
    redF[t] = fv[b*512 + t] + fv[b*512 + 256 + t];
    __syncthreads();
    for (int s2 = 128; s2 > 0; s2 >>= 1) {
        if (t < s2) redF[t] += redF[t + s2];
        __syncthreads();
    }
    float invF = 1.0f / redF[0];
    float a0 = 0.f;
#pragma unroll 8
    for (int d = 0; d < 256; ++d) a0 += W2t[d*256 + t] * svsh[d];
    out[((long)b*512)*256 + t] = fmaxf(row0pre[b*256 + t] - invF*a0, 0.f);
}

extern "C" void kernel_launch(void* const* d_in, const int* in_sizes, int n_in,
                              void* d_out, int out_size, void* d_ws, size_t ws_size,
                              hipStream_t stream) {
    const float* input   = (const float*)d_in[0];
    const float* Wp      = (const float*)d_in[1];
    const float* bp      = (const float*)d_in[2];
    const float* Wbil    = (const float*)d_in[3];
    const float* bbil    = (const float*)d_in[4];
    const float* Wfi     = (const float*)d_in[5];
    const float* bfi     = (const float*)d_in[6];
    const float* exparam = (const float*)d_in[7];
    const float* Wfz     = (const float*)d_in[8];
    const float* bfz     = (const float*)d_in[9];
    float* ws  = (float*)d_ws;
    float* out = (float*)d_out;

    float*  T     = ws + OFF_T;
    ushort* Qt16  = (ushort*)(ws + OFF_QT16);
    ushort* W116  = (ushort*)(ws + OFF_W116);
    float*  W2t   = ws + OFF_W2T;
    float*  v1    = ws + OFF_V1;
    float*  c1    = ws + OFF_C1;
    float*  h     = ws + OFF_H;
    float*  c0    = ws + OFF_C0;
    float*  Ev    = ws + OFF_EV;
    float*  fv    = ws + OFF_FV;
    float*  sump  = ws + OFF_SUMP;
    float*  v2b   = ws + OFF_V2B;
    float*  row0p = ws + OFF_ROW0;

    k0a<<<256, 256, 0, stream>>>(Wp, bp, Wbil, Wfz, exparam, T, W116, W2t, v1, h, c0);
    k0b<<<256, 256, 0, stream>>>(Wp, T, h, Qt16, c1);
    k_rowstats<<<ROWS_/64, 256, 0, stream>>>(input, Qt16, c1, c0, Wfi, bbil, bfi, W2t, Ev, fv, v2b);
    k_final<<<ROWS_/64, 256, 0, stream>>>(input, W116, v1, v2b, Ev, fv, bfz, sump, row0p, out);
    k_fix<<<B_, 256, 0, stream>>>(sump, fv, W2t, row0p, out);
}

// Round 8
// 97.929 us; speedup vs baseline: 1.8749x; 1.0903x over previous
//
#include <hip/hip_runtime.h>
#include <math.h>

#define B_    64
#define N_    512
#define SEM_  256
#define STR_  256
#define DIM_  512              // SEM+STR
#define ROWS_ (B_*N_)          // 32768

// ---- workspace layout (float offsets) ----
#define OFF_T      0           // 256x256 f32 (Wbil@Wp temp)
#define OFF_QT16   65536       // 256x256 bf16, Qt[e][d] = Q[d][e]
#define OFF_W116   98304       // 256x256 bf16, W116[o][d] = Wfz[o][d]
#define OFF_W2T    131072      // 256x256 f32, W2t[d][o] = Wfz[o][256+d]
#define OFF_V1     196608      // 256  Wfz2 @ exparam
#define OFF_C1     196864      // 256  Wp^T (Wbil+Wbil^T) bp
#define OFF_H      197120      // 256
#define OFF_C0     197376      // 1 (padded)
#define OFF_EV     197440      // 32768
#define OFF_FV     230208      // 32768
#define OFF_SUMP   262976      // 512*256 per-block partial sums
#define OFF_V2B    394048      // 64*256
#define OFF_ROW0   410432      // 64*256 pre-ReLU row-0 GEMM results

typedef __bf16 bf16x8 __attribute__((ext_vector_type(8)));
typedef float  f32x4  __attribute__((ext_vector_type(4)));

__device__ __forceinline__ ushort f2b(float x) {
    return __builtin_bit_cast(ushort, (__bf16)x);   // native v_cvt (RTNE)
}
__device__ __forceinline__ float bflo(unsigned u) {
    return __builtin_bit_cast(float, u << 16);
}
__device__ __forceinline__ float bfhi(unsigned u) {
    return __builtin_bit_cast(float, u & 0xffff0000u);
}

// ============ K0a: T = Wbil@Wp ; W116 ; W2t ; v1, h, c0 ============
__global__ __launch_bounds__(256) void k0a(
    const float* __restrict__ Wp, const float* __restrict__ bp,
    const float* __restrict__ Wbil, const float* __restrict__ Wfz,
    const float* __restrict__ exparam,
    float* __restrict__ T, ushort* __restrict__ W116, float* __restrict__ W2t,
    float* __restrict__ v1, float* __restrict__ h, float* __restrict__ c0)
{
    int t = threadIdx.x, a = blockIdx.x;
    float acc = 0.f;
    const float* wb = Wbil + a*256;
#pragma unroll 16
    for (int c = 0; c < 256; ++c) acc += wb[c] * Wp[c*256 + t];
    T[a*256 + t] = acc;
    W116[a*256 + t] = f2b(Wfz[a*512 + t]);
    W2t[t*256 + a] = Wfz[a*512 + 256 + t];          // transposed Wfz2
    if (a == 0) {
        float s = 0.f;
        const float* w2 = Wfz + t*512 + 256;
#pragma unroll 16
        for (int dd = 0; dd < 256; ++dd) s += w2[dd] * exparam[dd];
        v1[t] = s;
    }
    if (a == 1) {
        float g = 0.f, g2 = 0.f;
#pragma unroll 8
        for (int c = 0; c < 256; ++c) {
            g  += Wbil[t*256 + c] * bp[c];
            g2 += Wbil[c*256 + t] * bp[c];
        }
        h[t] = g + g2;
        __shared__ float red[256];
        red[t] = bp[t] * g;
        __syncthreads();
        for (int s2 = 128; s2 > 0; s2 >>= 1) {
            if (t < s2) red[t] += red[t + s2];
            __syncthreads();
        }
        if (t == 0) c0[0] = red[0];
    }
}

// ============ K0b: Qt16[e][t] = bf16(Q[t][e]) coalesced ; c1 ============
__global__ __launch_bounds__(256) void k0b(
    const float* __restrict__ Wp, const float* __restrict__ T,
    const float* __restrict__ h,
    ushort* __restrict__ Qt16, float* __restrict__ c1)
{
    int t = threadIdx.x, e = blockIdx.x;
    float acc = 0.f;
#pragma unroll 16
    for (int a2 = 0; a2 < 256; ++a2) acc += Wp[a2*256 + t] * T[a2*256 + e];
    Qt16[e*256 + t] = f2b(acc);          // Qt[e][d=t] = Q[d][e], coalesced store
    __shared__ float red[256];
    red[t] = Wp[t*256 + e] * h[t];
    __syncthreads();
    for (int s2 = 128; s2 > 0; s2 >>= 1) {
        if (t < s2) red[t] += red[t + s2];
        __syncthreads();
    }
    if (t == 0) c1[e] = red[0];
}

// ============ K1: MFMA GEMM u = str@Q -> Ev, fv via diag-MFMA ============
// LDS exactly 53248 B -> 3 blocks/CU (12 waves). B staged in LDS (R4 k-loop).
__global__ __launch_bounds__(256, 3) void k_rowstats(
    const float* __restrict__ input, const ushort* __restrict__ Qt16,
    const float* __restrict__ c1, const float* __restrict__ c0,
    const float* __restrict__ Wfi, const float* __restrict__ bbil,
    const float* __restrict__ bfi, const float* __restrict__ W2t,
    float* __restrict__ Ev, float* __restrict__ fv, float* __restrict__ v2b)
{
    __shared__ __align__(16) char smem[53248];
    ushort* Ash   = (ushort*)smem;              // [64][256] bf16, XOR-swizzled
    ushort* Bsm   = (ushort*)(smem + 32768);    // [256][40] bf16 k-slice (k-loop)
    ushort* Ush   = (ushort*)(smem + 32768);    // [64][128] bf16 swz (epilogue overlay)
    float*  sdiag = (float*)(smem + 49152);     // [64][4]   (epilogue overlay)
    float*  fdiag = (float*)(smem + 50176);     // [64][4]
    float*  s0sh  = (float*)(smem + 51200);     // [256]
    float*  shE0  = (float*)(smem + 52224);

    int t = threadIdx.x;
    int lane = t & 63, w = t >> 6;
    int g = lane >> 4, li = lane & 15;
    long rowbase = (long)blockIdx.x * 64;
    int b = (int)(rowbase >> 9);
    int i0 = (int)(rowbase & 511);
    const float* Ab = input + rowbase*DIM_ + SEM_;   // str half
    int xs = (li & 7) << 3;

    // stage A (str) tile: fp32 -> bf16, swizzled
#pragma unroll
    for (int q = 0; q < 16; ++q) {
        int v = t + 256*q;
        int r = v >> 6, c4 = v & 63;
        float4 a4 = *(const float4*)(Ab + (long)r*DIM_ + c4*4);
        ushort4 b4 = make_ushort4(f2b(a4.x), f2b(a4.y), f2b(a4.z), f2b(a4.w));
        *(ushort4*)&Ash[r*256 + ((c4*4) ^ ((r & 7) << 3))] = b4;
    }

    f32x4 acc[4][4];
#pragma unroll
    for (int m = 0; m < 4; ++m)
#pragma unroll
        for (int n = 0; n < 4; ++n) acc[m][n] = (f32x4){0.f, 0.f, 0.f, 0.f};

    for (int k0 = 0; k0 < 256; k0 += 32) {
        // stage B slice: Bsm[e][kk] = Qt16[e*256 + k0+kk]
#pragma unroll
        for (int q = 0; q < 4; ++q) {
            int v = t + 256*q;
            int n = v >> 2, c = v & 3;
            *(uint4*)&Bsm[n*40 + c*8] = *(const uint4*)&Qt16[n*256 + k0 + c*8];
        }
        __syncthreads();
        bf16x8 af[4], bfr[4];
#pragma unroll
        for (int m = 0; m < 4; ++m)
            af[m] = *(const bf16x8*)&Ash[(m*16 + li)*256 + ((k0 + g*8) ^ xs)];
#pragma unroll
        for (int n = 0; n < 4; ++n)
            bfr[n] = *(const bf16x8*)&Bsm[(w*64 + n*16 + li)*40 + g*8];
#pragma unroll
        for (int m = 0; m < 4; ++m)
#pragma unroll
            for (int n = 0; n < 4; ++n)
                acc[m][n] = __builtin_amdgcn_mfma_f32_16x16x32_bf16(af[m], bfr[n], acc[m][n], 0, 0, 0);
        __syncthreads();
    }

    // ---- epilogue: s = diag(U' Str^T), f = Wfi variant; U' in halved LDS ----
    float c1v[4];
#pragma unroll
    for (int n = 0; n < 4; ++n) c1v[n] = c1[w*64 + n*16 + li];

    f32x4 dacc[4], facc[4];
#pragma unroll
    for (int m = 0; m < 4; ++m) { dacc[m] = (f32x4){0.f,0.f,0.f,0.f}; facc[m] = (f32x4){0.f,0.f,0.f,0.f}; }

#pragma unroll
    for (int hv = 0; hv < 2; ++hv) {
        if ((w >> 1) == hv) {           // waves {0,1} stage cols 0..127; {2,3} stage 128..255
            int cl0 = (w & 1)*64;
#pragma unroll
            for (int m = 0; m < 4; ++m)
#pragma unroll
                for (int n = 0; n < 4; ++n)
#pragma unroll
                    for (int reg = 0; reg < 4; ++reg) {
                        int row = m*16 + g*4 + reg;
                        int cl = cl0 + n*16 + li;
                        Ush[row*128 + (cl ^ ((row & 7) << 3))] = f2b(acc[m][n][reg] + c1v[n]);
                    }
        }
        __syncthreads();
        int kb = w*32 + g*8;           // local k in half
        int kg = hv*128 + kb;          // global col
        float4 wf0 = *(const float4*)(Wfi + kg);
        float4 wf1 = *(const float4*)(Wfi + kg + 4);
        bf16x8 afw = (bf16x8){(__bf16)wf0.x, (__bf16)wf0.y, (__bf16)wf0.z, (__bf16)wf0.w,
                              (__bf16)wf1.x, (__bf16)wf1.y, (__bf16)wf1.z, (__bf16)wf1.w};
#pragma unroll
        for (int m = 0; m < 4; ++m) {
            bf16x8 afu = *(const bf16x8*)&Ush[(m*16 + li)*128 + (kb ^ xs)];
            bf16x8 bfs = *(const bf16x8*)&Ash[(m*16 + li)*256 + (kg ^ xs)];
            dacc[m] = __builtin_amdgcn_mfma_f32_16x16x32_bf16(afu, bfs, dacc[m], 0, 0, 0);
            facc[m] = __builtin_amdgcn_mfma_f32_16x16x32_bf16(afw, bfs, facc[m], 0, 0, 0);
        }
        __syncthreads();
    }

    // diag extraction: lane owns D[row=g*4+reg][col=li]; diag when li == g*4+reg
    if (g == (li >> 2)) {
        int dr = li & 3;
#pragma unroll
        for (int m = 0; m < 4; ++m) {
            float dv = dr == 0 ? dacc[m][0] : dr == 1 ? dacc[m][1] : dr == 2 ? dacc[m][2] : dacc[m][3];
            sdiag[(m*16 + li)*4 + w] = dv;
        }
    }
    if (g == 0) {
#pragma unroll
        for (int m = 0; m < 4; ++m) fdiag[(m*16 + li)*4 + w] = facc[m][0];
    }
    __syncthreads();
    if (t < 64) {
        float ss = sdiag[t*4] + sdiag[t*4+1] + sdiag[t*4+2] + sdiag[t*4+3];
        float ff = fdiag[t*4] + fdiag[t*4+1] + fdiag[t*4+2] + fdiag[t*4+3];
        float ev = expf(ss + c0[0] + bbil[0]);
        Ev[rowbase + t] = ev;
        fv[rowbase + t] = expf(ff + bfi[0]);
        if (t == 0) shE0[0] = ev;
    }

    // v2b for the block owning batch row 0
    if (i0 == 0) {
        if (t < 64)
            *(float4*)&s0sh[t*4] = *(const float4*)(input + (long)b*512*DIM_ + t*4);
        __syncthreads();
        float a2 = 0.f;
#pragma unroll 8
        for (int d = 0; d < 256; ++d) a2 += W2t[d*256 + t] * s0sh[d];
        v2b[b*256 + t] = shE0[0] * a2;
    }
}

// ============ K3: MFMA GEMM sem@Wfz1^T + epilogue + sump partials ============
// LDS exactly 53248 B -> 3 blocks/CU. B staged in LDS (R4 k-loop).
__global__ __launch_bounds__(256, 3) void k_final(
    const float* __restrict__ input, const ushort* __restrict__ W116,
    const float* __restrict__ v1, const float* __restrict__ v2b,
    const float* __restrict__ Ev, const float* __restrict__ fv,
    const float* __restrict__ bfz,
    float* __restrict__ sump, float* __restrict__ row0pre,
    float* __restrict__ out)
{
    __shared__ __align__(16) char smem[53248];
    ushort* Ash    = (ushort*)smem;             // [64][256] bf16 swz
    float*  Csh    = (float*)smem;              // [32][256] f32 swz (exact Ash overlay)
    ushort* Bsm    = (ushort*)(smem + 32768);   // [256][40] (k-loop)
    float*  sumred = (float*)(smem + 32768);    // [8][256]  (post-loop overlay)
    float*  cAs    = (float*)(smem + 40960);    // 64
    float*  cBs    = (float*)(smem + 41216);    // 64
    float*  EvL    = (float*)(smem + 41472);    // 64
    float*  wred   = (float*)(smem + 41728);    // 4

    int t = threadIdx.x;
    int lane = t & 63, w = t >> 6;
    int g = lane >> 4, li = lane & 15;
    long rowbase = (long)blockIdx.x * 64;
    int b = (int)(rowbase >> 9);
    int i0 = (int)(rowbase & 511);
    const float* Ab = input + rowbase*DIM_;          // sem half
    int xs = (li & 7) << 3;

    // stage A (sem) tile, swizzled
#pragma unroll
    for (int q = 0; q < 16; ++q) {
        int v = t + 256*q;
        int r = v >> 6, c4 = v & 63;
        float4 a4 = *(const float4*)(Ab + (long)r*DIM_ + c4*4);
        ushort4 b4 = make_ushort4(f2b(a4.x), f2b(a4.y), f2b(a4.z), f2b(a4.w));
        *(ushort4*)&Ash[r*256 + ((c4*4) ^ ((r & 7) << 3))] = b4;
    }

    f32x4 acc[4][4];
#pragma unroll
    for (int m = 0; m < 4; ++m)
#pragma unroll
        for (int n = 0; n < 4; ++n) acc[m][n] = (f32x4){0.f, 0.f, 0.f, 0.f};

    for (int k0 = 0; k0 < 256; k0 += 32) {
#pragma unroll
        for (int q = 0; q < 4; ++q) {
            int v = t + 256*q;
            int n = v >> 2, c = v & 3;
            *(uint4*)&Bsm[n*40 + c*8] = *(const uint4*)&W116[n*256 + k0 + c*8];
        }
        __syncthreads();
        bf16x8 af[4], bfr[4];
#pragma unroll
        for (int m = 0; m < 4; ++m)
            af[m] = *(const bf16x8*)&Ash[(m*16 + li)*256 + ((k0 + g*8) ^ xs)];
#pragma unroll
        for (int n = 0; n < 4; ++n)
            bfr[n] = *(const bf16x8*)&Bsm[(w*64 + n*16 + li)*40 + g*8];
#pragma unroll
        for (int m = 0; m < 4; ++m)
#pragma unroll
            for (int n = 0; n < 4; ++n)
                acc[m][n] = __builtin_amdgcn_mfma_f32_16x16x32_bf16(af[m], bfr[n], acc[m][n], 0, 0, 0);
        __syncthreads();
    }

    // ---- batch-stat setup (post-loop: Bsm dead, overlay region live) ----
    float fsum = fv[b*512 + t] + fv[b*512 + 256 + t];
#pragma unroll
    for (int off = 32; off >= 1; off >>= 1) fsum += __shfl_down(fsum, off);
    if (lane == 0) wred[w] = fsum;
    __syncthreads();
    float invF = 1.0f / (wred[0] + wred[1] + wred[2] + wred[3]);

    if (t < 64) {
        int row = (int)rowbase + t;
        float fr = fv[row];
        float ev = Ev[row];
        EvL[t] = (i0 == 0 && t == 0) ? 0.f : ev;     // exclude j=0 from sump
        cAs[t] = fr * invF;                          // d0
        cBs[t] = ((i0 + t) == 0) ? -invF
               : (1.0f + (fv[b*512] - fr)*invF) / (512.0f * ev);
    }
    __syncthreads();

    // ---- sump partial: sum_{j in block, j!=0} Ev_j * sem[j][d], vectorized ----
    {
        int qq = t >> 5, c8 = t & 31;
        float p[8];
#pragma unroll
        for (int i = 0; i < 8; ++i) p[i] = 0.f;
#pragma unroll
        for (int rr = 0; rr < 8; ++rr) {
            int r = qq*8 + rr;
            float ev = EvL[r];
            uint4 uv = *(const uint4*)&Ash[r*256 + ((c8*8) ^ (rr << 3))];
            p[0] += ev * bflo(uv.x); p[1] += ev * bfhi(uv.x);
            p[2] += ev * bflo(uv.y); p[3] += ev * bfhi(uv.y);
            p[4] += ev * bflo(uv.z); p[5] += ev * bfhi(uv.z);
            p[6] += ev * bflo(uv.w); p[7] += ev * bfhi(uv.w);
        }
        *(float4*)&sumred[qq*256 + c8*8]     = (float4){p[0], p[1], p[2], p[3]};
        *(float4*)&sumred[qq*256 + c8*8 + 4] = (float4){p[4], p[5], p[6], p[7]};
    }
    __syncthreads();
    {
        float sp = 0.f;
#pragma unroll
        for (int qq = 0; qq < 8; ++qq) sp += sumred[qq*256 + t];
        sump[(long)blockIdx.x*256 + t] = sp;
    }

    // epilogue vectors
    float v1v[4], v2v[4], bzv[4];
#pragma unroll
    for (int n = 0; n < 4; ++n) {
        int col = w*64 + n*16 + li;
        v1v[n] = v1[col];
        v2v[n] = v2b[b*256 + col];
        bzv[n] = bfz[col];
    }

    // two-half Csh repack (exact Ash overlay; stride 256, XOR col^(g<<3))
#pragma unroll
    for (int hh = 0; hh < 2; ++hh) {
        __syncthreads();   // all Ash reads (k-loop/sump) or prior store reads done
#pragma unroll
        for (int mm = 0; mm < 2; ++mm) {
            int m = hh*2 + mm;
#pragma unroll
            for (int reg = 0; reg < 4; ++reg) {
                int row = m*16 + g*4 + reg;
                int row_l = row - hh*32;
                int sw = ((row_l >> 2) & 3) << 3;
                float ca = cAs[row], cb = cBs[row];
                int irow = i0 + row;
#pragma unroll
                for (int n = 0; n < 4; ++n) {
                    int col = w*64 + n*16 + li;
                    float sel = (irow == 0) ? 0.f : v2v[n];
                    float val = acc[m][n][reg] + ca*v1v[n] + cb*sel + bzv[n];
                    if (irow == 0) row0pre[b*256 + col] = val;   // pre-ReLU, no v0 term
                    Csh[row_l*256 + (col ^ sw)] = fmaxf(val, 0.f);
                }
            }
        }
        __syncthreads();
#pragma unroll
        for (int q = 0; q < 8; ++q) {
            int v = t + 256*q;
            int r = v >> 6, c4 = v & 63;
            int sw = ((r >> 2) & 3) << 3;
            *(float4*)(out + (rowbase + hh*32 + r)*256 + c4*4) =
                *(const float4*)&Csh[r*256 + ((c4*4) ^ sw)];
        }
    }
}

// ============ K4: fixup row i=0 of each batch ============
__global__ __launch_bounds__(256) void k_fix(
    const float* __restrict__ sump, const float* __restrict__ fv,
    const float* __restrict__ W2t, const float* __restrict__ row0pre,
    float* __restrict__ out)
{
    int b = blockIdx.x, t = threadIdx.x;
    __shared__ float svsh[256];
    __shared__ float redF[256];
    float a = 0.f;
#pragma unroll
    for (int p = 0; p < 8; ++p) a += sump[(long)(b*8 + p)*256 + t];
    svsh[t] = a;
    redF[t] = fv[b*512 + t] + fv[b*512 + 256 + t];
    __syncthreads();
    for (int s2 = 128; s2 > 0; s2 >>= 1) {
        if (t < s2) redF[t] += redF[t + s2];
        __syncthreads();
    }
    float invF = 1.0f / redF[0];
    float a0 = 0.f;
#pragma unroll 8
    for (int d = 0; d < 256; ++d) a0 += W2t[d*256 + t] * svsh[d];
    out[((long)b*512)*256 + t] = fmaxf(row0pre[b*256 + t] - invF*a0, 0.f);
}

extern "C" void kernel_launch(void* const* d_in, const int* in_sizes, int n_in,
                              void* d_out, int out_size, void* d_ws, size_t ws_size,
                              hipStream_t stream) {
    const float* input   = (const float*)d_in[0];
    const float* Wp      = (const float*)d_in[1];
    const float* bp      = (const float*)d_in[2];
    const float* Wbil    = (const float*)d_in[3];
    const float* bbil    = (const float*)d_in[4];
    const float* Wfi     = (const float*)d_in[5];
    const float* bfi     = (const float*)d_in[6];
    const float* exparam = (const float*)d_in[7];
    const float* Wfz     = (const float*)d_in[8];
    const float* bfz     = (const float*)d_in[9];
    float* ws  = (float*)d_ws;
    float* out = (float*)d_out;

    float*  T     = ws + OFF_T;
    ushort* Qt16  = (ushort*)(ws + OFF_QT16);
    ushort* W116  = (ushort*)(ws + OFF_W116);
    float*  W2t   = ws + OFF_W2T;
    float*  v1    = ws + OFF_V1;
    float*  c1    = ws + OFF_C1;
    float*  h     = ws + OFF_H;
    float*  c0    = ws + OFF_C0;
    float*  Ev    = ws + OFF_EV;
    float*  fv    = ws + OFF_FV;
    float*  sump  = ws + OFF_SUMP;
    float*  v2b   = ws + OFF_V2B;
    float*  row0p = ws + OFF_ROW0;

    k0a<<<256, 256, 0, stream>>>(Wp, bp, Wbil, Wfz, exparam, T, W116, W2t, v1, h, c0);
    k0b<<<256, 256, 0, stream>>>(Wp, T, h, Qt16, c1);
    k_rowstats<<<ROWS_/64, 256, 0, stream>>>(input, Qt16, c1, c0, Wfi, bbil, bfi, W2t, Ev, fv, v2b);
    k_final<<<ROWS_/64, 256, 0, stream>>>(input, W116, v1, v2b, Ev, fv, bfz, sump, row0p, out);
    k_fix<<<B_, 256, 0, stream>>>(sump, fv, W2t, row0p, out);
}

// Round 9
// 84.045 us; speedup vs baseline: 2.1846x; 1.1652x over previous
//
#include <hip/hip_runtime.h>
#include <math.h>

#define B_    64
#define N_    512
#define SEM_  256
#define STR_  256
#define DIM_  512              // SEM+STR
#define ROWS_ (B_*N_)          // 32768

// ---- workspace layout (float offsets) ----
#define OFF_T      0           // 256x256 f32 (Wbil@Wp temp)
#define OFF_QT16   65536       // 256x256 bf16, Qt[e][d] = Q[d][e]
#define OFF_W116   98304       // 256x256 bf16, W116[o][d] = Wfz[o][d]
#define OFF_W2T    131072      // 256x256 f32, W2t[d][o] = Wfz[o][256+d]
#define OFF_V1     196608      // 256  Wfz2 @ exparam
#define OFF_C1     196864      // 256  Wp^T (Wbil+Wbil^T) bp
#define OFF_H      197120      // 256
#define OFF_C0     197376      // 1 (padded)
#define OFF_EV     197440      // 32768
#define OFF_FV     230208      // 32768
#define OFF_SUMP   262976      // 512*256 per-block partial sums
#define OFF_V2B    394048      // 64*256
#define OFF_ROW0   410432      // 64*256 pre-ReLU row-0 GEMM results

typedef __bf16 bf16x8 __attribute__((ext_vector_type(8)));
typedef float  f32x4  __attribute__((ext_vector_type(4)));

__device__ __forceinline__ ushort f2b(float x) {
    return __builtin_bit_cast(ushort, (__bf16)x);   // native v_cvt (RTNE)
}
__device__ __forceinline__ float bflo(unsigned u) {
    return __builtin_bit_cast(float, u << 16);
}
__device__ __forceinline__ float bfhi(unsigned u) {
    return __builtin_bit_cast(float, u & 0xffff0000u);
}

// ============ K0a: T = Wbil@Wp ; W116 ; W2t ; v1, h, c0 ============
__global__ __launch_bounds__(256) void k0a(
    const float* __restrict__ Wp, const float* __restrict__ bp,
    const float* __restrict__ Wbil, const float* __restrict__ Wfz,
    const float* __restrict__ exparam,
    float* __restrict__ T, ushort* __restrict__ W116, float* __restrict__ W2t,
    float* __restrict__ v1, float* __restrict__ h, float* __restrict__ c0)
{
    int t = threadIdx.x, a = blockIdx.x;
    float acc = 0.f;
    const float* wb = Wbil + a*256;
#pragma unroll 32
    for (int c = 0; c < 256; ++c) acc += wb[c] * Wp[c*256 + t];
    T[a*256 + t] = acc;
    W116[a*256 + t] = f2b(Wfz[a*512 + t]);
    W2t[t*256 + a] = Wfz[a*512 + 256 + t];          // transposed Wfz2
    if (a == 0) {
        float s = 0.f;
        const float* w2 = Wfz + t*512 + 256;
#pragma unroll 32
        for (int dd = 0; dd < 256; ++dd) s += w2[dd] * exparam[dd];
        v1[t] = s;
    }
    if (a == 1) {
        float g = 0.f, g2 = 0.f;
#pragma unroll 16
        for (int c = 0; c < 256; ++c) {
            g  += Wbil[t*256 + c] * bp[c];
            g2 += Wbil[c*256 + t] * bp[c];
        }
        h[t] = g + g2;
        __shared__ float red[256];
        red[t] = bp[t] * g;
        __syncthreads();
        for (int s2 = 128; s2 > 0; s2 >>= 1) {
            if (t < s2) red[t] += red[t + s2];
            __syncthreads();
        }
        if (t == 0) c0[0] = red[0];
    }
}

// ============ K0b: Qt16[e][t] = bf16(Q[t][e]) coalesced ; c1 ============
__global__ __launch_bounds__(256) void k0b(
    const float* __restrict__ Wp, const float* __restrict__ T,
    const float* __restrict__ h,
    ushort* __restrict__ Qt16, float* __restrict__ c1)
{
    int t = threadIdx.x, e = blockIdx.x;
    float acc = 0.f;
#pragma unroll 32
    for (int a2 = 0; a2 < 256; ++a2) acc += Wp[a2*256 + t] * T[a2*256 + e];
    Qt16[e*256 + t] = f2b(acc);          // Qt[e][d=t] = Q[d][e], coalesced store
    __shared__ float red[256];
    red[t] = Wp[t*256 + e] * h[t];
    __syncthreads();
    for (int s2 = 128; s2 > 0; s2 >>= 1) {
        if (t < s2) red[t] += red[t + s2];
        __syncthreads();
    }
    if (t == 0) c1[e] = red[0];
}

// ============ K1: MFMA GEMM u = str@Q -> Ev, fv via diag-MFMA ============
// R4 body + double-buffered B slices (1 barrier/iter, loads hidden under MFMA).
__global__ __launch_bounds__(256) void k_rowstats(
    const float* __restrict__ input, const ushort* __restrict__ Qt16,
    const float* __restrict__ c1, const float* __restrict__ c0,
    const float* __restrict__ Wfi, const float* __restrict__ bbil,
    const float* __restrict__ bfi, const float* __restrict__ W2t,
    float* __restrict__ Ev, float* __restrict__ fv, float* __restrict__ v2b)
{
    __shared__ __align__(16) char smem[73728];
    ushort* Ash   = (ushort*)smem;              // [64][256] bf16, XOR-swizzled
    ushort* Bsm0  = (ushort*)(smem + 32768);    // [256][40] bf16 (dbuf 0)
    ushort* Bsm1  = (ushort*)(smem + 53248);    // [256][40] bf16 (dbuf 1)
    ushort* Ush   = (ushort*)(smem + 32768);    // [64][256] bf16 swz (epilogue overlay)
    float*  sdiag = (float*)(smem + 65536);     // [64][4]   (epilogue overlay)
    float*  fdiag = (float*)(smem + 66560);     // [64][4]
    float*  s0sh  = (float*)(smem + 67584);     // [256]
    float*  shE0  = (float*)(smem + 68608);

    int t = threadIdx.x;
    int lane = t & 63, w = t >> 6;
    int g = lane >> 4, li = lane & 15;
    long rowbase = (long)blockIdx.x * 64;
    int b = (int)(rowbase >> 9);
    int i0 = (int)(rowbase & 511);
    const float* Ab = input + rowbase*DIM_ + SEM_;   // str half
    int xs = (li & 7) << 3;
    int sn = t >> 2, sc = t & 3;                     // B-stage indices

    // stage A (str) tile: fp32 -> bf16, swizzled
#pragma unroll
    for (int q = 0; q < 16; ++q) {
        int v = t + 256*q;
        int r = v >> 6, c4 = v & 63;
        float4 a4 = *(const float4*)(Ab + (long)r*DIM_ + c4*4);
        ushort4 b4 = make_ushort4(f2b(a4.x), f2b(a4.y), f2b(a4.z), f2b(a4.w));
        *(ushort4*)&Ash[r*256 + ((c4*4) ^ ((r & 7) << 3))] = b4;
    }
    // prologue: stage B slice 0 into Bsm0
#pragma unroll
    for (int q = 0; q < 4; ++q) {
        int v = t + 256*q;
        int n = v >> 2, c = v & 3;
        *(uint4*)&Bsm0[n*40 + c*8] = *(const uint4*)&Qt16[n*256 + c*8];
    }
    __syncthreads();

    f32x4 acc[4][4];
#pragma unroll
    for (int m = 0; m < 4; ++m)
#pragma unroll
        for (int n = 0; n < 4; ++n) acc[m][n] = (f32x4){0.f, 0.f, 0.f, 0.f};

#pragma unroll
    for (int ks = 0; ks < 8; ++ks) {
        ushort* Bcur = (ks & 1) ? Bsm1 : Bsm0;
        ushort* Bnxt = (ks & 1) ? Bsm0 : Bsm1;
        int k0 = ks*32;
        uint4 breg[4];
        if (ks < 7) {   // issue next-slice loads early (latency hides under MFMA)
#pragma unroll
            for (int q = 0; q < 4; ++q) {
                int v = t + 256*q;
                int n = v >> 2, c = v & 3;
                breg[q] = *(const uint4*)&Qt16[n*256 + (k0 + 32) + c*8];
            }
        }
        bf16x8 af[4], bfr[4];
#pragma unroll
        for (int m = 0; m < 4; ++m)
            af[m] = *(const bf16x8*)&Ash[(m*16 + li)*256 + ((k0 + g*8) ^ xs)];
#pragma unroll
        for (int n = 0; n < 4; ++n)
            bfr[n] = *(const bf16x8*)&Bcur[(w*64 + n*16 + li)*40 + g*8];
#pragma unroll
        for (int m = 0; m < 4; ++m)
#pragma unroll
            for (int n = 0; n < 4; ++n)
                acc[m][n] = __builtin_amdgcn_mfma_f32_16x16x32_bf16(af[m], bfr[n], acc[m][n], 0, 0, 0);
        if (ks < 7) {   // write next slice late
#pragma unroll
            for (int q = 0; q < 4; ++q) {
                int v = t + 256*q;
                int n = v >> 2, c = v & 3;
                *(uint4*)&Bnxt[n*40 + c*8] = breg[q];
            }
        }
        __syncthreads();
    }

    // ---- U' = u + c1 -> Ush (bf16, swizzled) ----
    float c1v[4];
#pragma unroll
    for (int n = 0; n < 4; ++n) c1v[n] = c1[w*64 + n*16 + li];
#pragma unroll
    for (int m = 0; m < 4; ++m)
#pragma unroll
        for (int n = 0; n < 4; ++n)
#pragma unroll
            for (int reg = 0; reg < 4; ++reg) {
                int row = m*16 + g*4 + reg;
                int col = w*64 + n*16 + li;
                Ush[row*256 + (col ^ ((row & 7) << 3))] = f2b(acc[m][n][reg] + c1v[n]);
            }
    __syncthreads();

    // ---- diag MFMA: s = diag(U' @ Str^T), f = Wfi-broadcast variant ----
    f32x4 dacc[4], facc[4];
#pragma unroll
    for (int m = 0; m < 4; ++m) { dacc[m] = (f32x4){0.f,0.f,0.f,0.f}; facc[m] = (f32x4){0.f,0.f,0.f,0.f}; }
#pragma unroll
    for (int kk = 0; kk < 2; ++kk) {
        int kb = (w*2 + kk)*32 + g*8;
        float4 wf0 = *(const float4*)(Wfi + kb);
        float4 wf1 = *(const float4*)(Wfi + kb + 4);
        bf16x8 afw = (bf16x8){(__bf16)wf0.x, (__bf16)wf0.y, (__bf16)wf0.z, (__bf16)wf0.w,
                              (__bf16)wf1.x, (__bf16)wf1.y, (__bf16)wf1.z, (__bf16)wf1.w};
#pragma unroll
        for (int m = 0; m < 4; ++m) {
            int ridx = (m*16 + li)*256 + (kb ^ xs);
            bf16x8 afu = *(const bf16x8*)&Ush[ridx];
            bf16x8 bfs = *(const bf16x8*)&Ash[ridx];
            dacc[m] = __builtin_amdgcn_mfma_f32_16x16x32_bf16(afu, bfs, dacc[m], 0, 0, 0);
            facc[m] = __builtin_amdgcn_mfma_f32_16x16x32_bf16(afw, bfs, facc[m], 0, 0, 0);
        }
    }
    // extract diagonal: lane owns D[row=g*4+reg][col=li]; diag when li == g*4+reg
    if (g == (li >> 2)) {
        int dr = li & 3;
#pragma unroll
        for (int m = 0; m < 4; ++m) {
            float dv = dr == 0 ? dacc[m][0] : dr == 1 ? dacc[m][1] : dr == 2 ? dacc[m][2] : dacc[m][3];
            sdiag[(m*16 + li)*4 + w] = dv;
        }
    }
    if (g == 0) {
#pragma unroll
        for (int m = 0; m < 4; ++m) fdiag[(m*16 + li)*4 + w] = facc[m][0];
    }
    __syncthreads();
    if (t < 64) {
        float ss = sdiag[t*4] + sdiag[t*4+1] + sdiag[t*4+2] + sdiag[t*4+3];
        float ff = fdiag[t*4] + fdiag[t*4+1] + fdiag[t*4+2] + fdiag[t*4+3];
        float ev = expf(ss + c0[0] + bbil[0]);
        Ev[rowbase + t] = ev;
        fv[rowbase + t] = expf(ff + bfi[0]);
        if (t == 0) shE0[0] = ev;
    }

    // v2b for the block owning batch row 0
    if (i0 == 0) {
        if (t < 64)
            *(float4*)&s0sh[t*4] = *(const float4*)(input + (long)b*512*DIM_ + t*4);
        __syncthreads();
        float a2 = 0.f;
#pragma unroll 16
        for (int d = 0; d < 256; ++d) a2 += W2t[d*256 + t] * s0sh[d];
        v2b[b*256 + t] = shE0[0] * a2;
    }
}

// ============ K3: MFMA GEMM sem@Wfz1^T + epilogue + sump partials ============
// R4 body + double-buffered B slices.
__global__ __launch_bounds__(256) void k_final(
    const float* __restrict__ input, const ushort* __restrict__ W116,
    const float* __restrict__ v1, const float* __restrict__ v2b,
    const float* __restrict__ Ev, const float* __restrict__ fv,
    const float* __restrict__ bfz,
    float* __restrict__ sump, float* __restrict__ row0pre,
    float* __restrict__ out)
{
    __shared__ __align__(16) char smem[74752];
    ushort* Ash    = (ushort*)smem;             // [64][256] bf16 swz
    float*  Csh    = (float*)smem;              // [32][264] f32 (epilogue overlay)
    ushort* Bsm0   = (ushort*)(smem + 32768);   // [256][40] (dbuf 0)
    ushort* Bsm1   = (ushort*)(smem + 53248);   // [256][40] (dbuf 1)
    float*  sumred = (float*)(smem + 40960);    // [8][256] (post-loop overlay in Bsm0)
    float*  cAs    = (float*)(smem + 73728);    // 64
    float*  cBs    = (float*)(smem + 73984);    // 64
    float*  EvL    = (float*)(smem + 74240);    // 64
    float*  wred   = (float*)(smem + 74496);    // 4

    int t = threadIdx.x;
    int lane = t & 63, w = t >> 6;
    int g = lane >> 4, li = lane & 15;
    long rowbase = (long)blockIdx.x * 64;
    int b = (int)(rowbase >> 9);
    int i0 = (int)(rowbase & 511);
    const float* Ab = input + rowbase*DIM_;          // sem half
    int xs = (li & 7) << 3;

    // Fws = sum fv over batch via wave-shuffle reduce
    float fsum = fv[b*512 + t] + fv[b*512 + 256 + t];
#pragma unroll
    for (int off = 32; off >= 1; off >>= 1) fsum += __shfl_down(fsum, off);
    if (lane == 0) wred[w] = fsum;
    __syncthreads();
    float invF = 1.0f / (wred[0] + wred[1] + wred[2] + wred[3]);

    if (t < 64) {
        int row = (int)rowbase + t;
        float fr = fv[row];
        float ev = Ev[row];
        EvL[t] = (i0 == 0 && t == 0) ? 0.f : ev;     // exclude j=0 from sump
        cAs[t] = fr * invF;                          // d0
        cBs[t] = ((i0 + t) == 0) ? -invF
               : (1.0f + (fv[b*512] - fr)*invF) / (512.0f * ev);
    }

    // stage A (sem) tile, swizzled
#pragma unroll
    for (int q = 0; q < 16; ++q) {
        int v = t + 256*q;
        int r = v >> 6, c4 = v & 63;
        float4 a4 = *(const float4*)(Ab + (long)r*DIM_ + c4*4);
        ushort4 b4 = make_ushort4(f2b(a4.x), f2b(a4.y), f2b(a4.z), f2b(a4.w));
        *(ushort4*)&Ash[r*256 + ((c4*4) ^ ((r & 7) << 3))] = b4;
    }
    // prologue: stage B slice 0
#pragma unroll
    for (int q = 0; q < 4; ++q) {
        int v = t + 256*q;
        int n = v >> 2, c = v & 3;
        *(uint4*)&Bsm0[n*40 + c*8] = *(const uint4*)&W116[n*256 + c*8];
    }
    __syncthreads();

    f32x4 acc[4][4];
#pragma unroll
    for (int m = 0; m < 4; ++m)
#pragma unroll
        for (int n = 0; n < 4; ++n) acc[m][n] = (f32x4){0.f, 0.f, 0.f, 0.f};

#pragma unroll
    for (int ks = 0; ks < 8; ++ks) {
        ushort* Bcur = (ks & 1) ? Bsm1 : Bsm0;
        ushort* Bnxt = (ks & 1) ? Bsm0 : Bsm1;
        int k0 = ks*32;
        uint4 breg[4];
        if (ks < 7) {
#pragma unroll
            for (int q = 0; q < 4; ++q) {
                int v = t + 256*q;
                int n = v >> 2, c = v & 3;
                breg[q] = *(const uint4*)&W116[n*256 + (k0 + 32) + c*8];
            }
        }
        bf16x8 af[4], bfr[4];
#pragma unroll
        for (int m = 0; m < 4; ++m)
            af[m] = *(const bf16x8*)&Ash[(m*16 + li)*256 + ((k0 + g*8) ^ xs)];
#pragma unroll
        for (int n = 0; n < 4; ++n)
            bfr[n] = *(const bf16x8*)&Bcur[(w*64 + n*16 + li)*40 + g*8];
#pragma unroll
        for (int m = 0; m < 4; ++m)
#pragma unroll
            for (int n = 0; n < 4; ++n)
                acc[m][n] = __builtin_amdgcn_mfma_f32_16x16x32_bf16(af[m], bfr[n], acc[m][n], 0, 0, 0);
        if (ks < 7) {
#pragma unroll
            for (int q = 0; q < 4; ++q) {
                int v = t + 256*q;
                int n = v >> 2, c = v & 3;
                *(uint4*)&Bnxt[n*40 + c*8] = breg[q];
            }
        }
        __syncthreads();
    }

    // ---- sump partial: sum_{j in block, j!=0} Ev_j * sem[j][d], vectorized ----
    {
        int qq = t >> 5, c8 = t & 31;
        float p[8];
#pragma unroll
        for (int i = 0; i < 8; ++i) p[i] = 0.f;
#pragma unroll
        for (int rr = 0; rr < 8; ++rr) {
            int r = qq*8 + rr;
            float ev = EvL[r];
            uint4 uv = *(const uint4*)&Ash[r*256 + ((c8*8) ^ (rr << 3))];
            p[0] += ev * bflo(uv.x); p[1] += ev * bfhi(uv.x);
            p[2] += ev * bflo(uv.y); p[3] += ev * bfhi(uv.y);
            p[4] += ev * bflo(uv.z); p[5] += ev * bfhi(uv.z);
            p[6] += ev * bflo(uv.w); p[7] += ev * bfhi(uv.w);
        }
        *(float4*)&sumred[qq*256 + c8*8]     = (float4){p[0], p[1], p[2], p[3]};
        *(float4*)&sumred[qq*256 + c8*8 + 4] = (float4){p[4], p[5], p[6], p[7]};
    }
    __syncthreads();
    {
        float sp = 0.f;
#pragma unroll
        for (int qq = 0; qq < 8; ++qq) sp += sumred[qq*256 + t];
        sump[(long)blockIdx.x*256 + t] = sp;
    }

    // epilogue vectors
    float v1v[4], v2v[4], bzv[4];
#pragma unroll
    for (int n = 0; n < 4; ++n) {
        int col = w*64 + n*16 + li;
        v1v[n] = v1[col];
        v2v[n] = v2b[b*256 + col];
        bzv[n] = bfz[col];
    }

    // two-half LDS repack (Csh overlaps Ash; all Ash reads completed above)
#pragma unroll
    for (int hh = 0; hh < 2; ++hh) {
        __syncthreads();
#pragma unroll
        for (int mm = 0; mm < 2; ++mm) {
            int m = hh*2 + mm;
#pragma unroll
            for (int reg = 0; reg < 4; ++reg) {
                int row = m*16 + g*4 + reg;
                float ca = cAs[row], cb = cBs[row];
                int irow = i0 + row;
#pragma unroll
                for (int n = 0; n < 4; ++n) {
                    int col = w*64 + n*16 + li;
                    float sel = (irow == 0) ? 0.f : v2v[n];
                    float val = acc[m][n][reg] + ca*v1v[n] + cb*sel + bzv[n];
                    if (irow == 0) row0pre[b*256 + col] = val;   // pre-ReLU, no v0 term
                    Csh[(row - hh*32)*264 + col] = fmaxf(val, 0.f);
                }
            }
        }
        __syncthreads();
#pragma unroll
        for (int q = 0; q < 8; ++q) {
            int v = t + 256*q;
            int r = v >> 6, c4 = v & 63;
            *(float4*)(out + (rowbase + hh*32 + r)*256 + c4*4) = *(const float4*)&Csh[r*264 + c4*4];
        }
    }
}

// ============ K4: fixup row i=0 of each batch ============
__global__ __launch_bounds__(256) void k_fix(
    const float* __restrict__ sump, const float* __restrict__ fv,
    const float* __restrict__ W2t, const float* __restrict__ row0pre,
    float* __restrict__ out)
{
    int b = blockIdx.x, t = threadIdx.x;
    __shared__ float svsh[256];
    __shared__ float redF[256];
    float a = 0.f;
#pragma unroll
    for (int p = 0; p < 8; ++p) a += sump[(long)(b*8 + p)*256 + t];
    svsh[t] = a;
    redF[t] = fv[b*512 + t] + fv[b*512 + 256 + t];
    __syncthreads();
    for (int s2 = 128; s2 > 0; s2 >>= 1) {
        if (t < s2) redF[t] += redF[t + s2];
        __syncthreads();
    }
    float invF = 1.0f / redF[0];
    float a0 = 0.f;
#pragma unroll 16
    for (int d = 0; d < 256; ++d) a0 += W2t[d*256 + t] * svsh[d];
    out[((long)b*512)*256 + t] = fmaxf(row0pre[b*256 + t] - invF*a0, 0.f);
}

extern "C" void kernel_launch(void* const* d_in, const int* in_sizes, int n_in,
                              void* d_out, int out_size, void* d_ws, size_t ws_size,
                              hipStream_t stream) {
    const float* input   = (const float*)d_in[0];
    const float* Wp      = (const float*)d_in[1];
    const float* bp      = (const float*)d_in[2];
    const float* Wbil    = (const float*)d_in[3];
    const float* bbil    = (const float*)d_in[4];
    const float* Wfi     = (const float*)d_in[5];
    const float* bfi     = (const float*)d_in[6];
    const float* exparam = (const float*)d_in[7];
    const float* Wfz     = (const float*)d_in[8];
    const float* bfz     = (const float*)d_in[9];
    float* ws  = (float*)d_ws;
    float* out = (float*)d_out;

    float*  T     = ws + OFF_T;
    ushort* Qt16  = (ushort*)(ws + OFF_QT16);
    ushort* W116  = (ushort*)(ws + OFF_W116);
    float*  W2t   = ws + OFF_W2T;
    float*  v1    = ws + OFF_V1;
    float*  c1    = ws + OFF_C1;
    float*  h     = ws + OFF_H;
    float*  c0    = ws + OFF_C0;
    float*  Ev    = ws + OFF_EV;
    float*  fv    = ws + OFF_FV;
    float*  sump  = ws + OFF_SUMP;
    float*  v2b   = ws + OFF_V2B;
    float*  row0p = ws + OFF_ROW0;

    k0a<<<256, 256, 0, stream>>>(Wp, bp, Wbil, Wfz, exparam, T, W116, W2t, v1, h, c0);
    k0b<<<256, 256, 0, stream>>>(Wp, T, h, Qt16, c1);
    k_rowstats<<<ROWS_/64, 256, 0, stream>>>(input, Qt16, c1, c0, Wfi, bbil, bfi, W2t, Ev, fv, v2b);
    k_final<<<ROWS_/64, 256, 0, stream>>>(input, W116, v1, v2b, Ev, fv, bfz, sump, row0p, out);
    k_fix<<<B_, 256, 0, stream>>>(sump, fv, W2t, row0p, out);
}